// Round 1
// baseline (481.757 us; speedup 1.0000x reference)
//
#include <hip/hip_runtime.h>
#include <cstdint>
#include <cstddef>

#define NE 8
#define HD 2048
#define IN 1408
#define NT 2048
#define NP (NT*2)
#define MAXMT 40

typedef __bf16 bf16;
typedef __bf16 bf16x8 __attribute__((ext_vector_type(8)));
typedef __bf16 bf16x4 __attribute__((ext_vector_type(4)));
typedef float f32x4 __attribute__((ext_vector_type(4)));

__device__ __forceinline__ void load_lds16(const void* g, void* l) {
  __builtin_amdgcn_global_load_lds((const __attribute__((address_space(1))) uint32_t*)g,
                                   (__attribute__((address_space(3))) uint32_t*)l, 16, 0, 0);
}

// ---------------- hidden f32 -> bf16 ----------------
__global__ void k_cvt(const float* __restrict__ x, bf16* __restrict__ y) {
  int i = blockIdx.x * 256 + threadIdx.x;           // covers NT*HD/4
  f32x4 v = ((const f32x4*)x)[i];
  bf16x4 o;
  o[0] = (bf16)v[0]; o[1] = (bf16)v[1]; o[2] = (bf16)v[2]; o[3] = (bf16)v[3];
  ((bf16x4*)y)[i] = o;
}

// ---------------- routing: bucket pairs by expert ----------------
__global__ void k_route(const int* __restrict__ idx, const float* __restrict__ w,
                        int* __restrict__ perm_tok, float* __restrict__ perm_w,
                        int* __restrict__ slot_of, int* __restrict__ tiles) {
  __shared__ int cnt[NE], off[NE + 1], rk[NE];
  int tid = threadIdx.x;
  if (tid < NE) { cnt[tid] = 0; rk[tid] = 0; }
  __syncthreads();
  for (int a = tid; a < NP; a += 256) atomicAdd(&cnt[idx[a]], 1);
  __syncthreads();
  if (tid == 0) { off[0] = 0; for (int e = 0; e < NE; e++) off[e + 1] = off[e] + cnt[e]; }
  __syncthreads();
  for (int a = tid; a < NP; a += 256) {
    int e = idx[a];
    int p = off[e] + atomicAdd(&rk[e], 1);
    perm_tok[p] = a >> 1;
    perm_w[p] = w[a];
    slot_of[a] = p;
  }
  __syncthreads();
  if (tid == 0) {
    int n = 0;
    for (int e = 0; e < NE; e++)
      for (int r = off[e]; r < off[e + 1]; r += 128) {
        tiles[n] = e; tiles[MAXMT + n] = r; tiles[2 * MAXMT + n] = off[e + 1];
        n++;
      }
    for (int s = n; s < MAXMT; s++) tiles[s] = -1;
  }
}

// ---------------- GEMM1: act = silu(X@Gw) * (X@Uw) * pair_w   (bf16 out) ----------------
// tile 128(M) x 128(N) x 64(K); 4 waves in 2x2; XOR-swizzled LDS (16B chunks)
__launch_bounds__(256, 2)
__global__ void k_gemm1(const bf16* __restrict__ hid, const float* __restrict__ gw,
                        const float* __restrict__ uw, const int* __restrict__ perm_tok,
                        const float* __restrict__ perm_w, const int* __restrict__ tiles,
                        bf16* __restrict__ act) {
  int b = blockIdx.x;
  int q = b >> 5, r5 = b & 31;
  int p = q * 8 + (r5 & 7);                 // (sg, nt) pair id; same p+sub -> same XCD
  if (p >= 110) return;
  int slot = (p / 11) * 4 + (r5 >> 3);
  int e = tiles[slot];
  if (e < 0) return;
  int nt = p % 11;
  int row0 = tiles[MAXMT + slot], rowend = tiles[2 * MAXMT + slot];
  int nb = nt * 128;

  __shared__ bf16 As[128 * 64];
  __shared__ bf16 Bg[128 * 64];
  __shared__ bf16 Bu[128 * 64];

  int tid = threadIdx.x;
  int lane = tid & 63, wave = tid >> 6;
  int wm = (wave >> 1) * 64, wn = (wave & 1) * 64;

  // A staging: slot s -> row r=s>>3, swizzled chunk col c=(s&7)^(r&7)
  const bf16* aG[4]; bf16* aL[4];
#pragma unroll
  for (int i2 = 0; i2 < 4; i2++) {
    int s = i2 * 256 + tid;
    int r = s >> 3, c = (s & 7) ^ (r & 7);
    int tr = row0 + r; if (tr > NP - 1) tr = NP - 1;
    aG[i2] = hid + (size_t)perm_tok[tr] * HD + c * 8;
    aL[i2] = As + s * 8;
  }
  // B staging: thread owns k-block kk..kk+7, n-cols nn..nn+3 (transpose to n-major)
  int kk = (tid & 7) * 8, nn = (tid >> 3) * 4;
  const float* gB = gw + (size_t)e * HD * IN + (size_t)kk * IN + (nb + nn);
  const float* uB = uw + (size_t)e * HD * IN + (size_t)kk * IN + (nb + nn);
  int bslot[4];
#pragma unroll
  for (int i2 = 0; i2 < 4; i2++) { int n = nn + i2; bslot[i2] = (n * 8 + ((tid & 7) ^ (n & 7))) * 8; }

  f32x4 accG[4][4] = {};
  f32x4 accU[4][4] = {};

  for (int k0 = 0; k0 < HD; k0 += 64) {
    __syncthreads();
#pragma unroll
    for (int i2 = 0; i2 < 4; i2++) load_lds16(aG[i2] + k0, aL[i2]);
    {
      f32x4 v[8];
#pragma unroll
      for (int j = 0; j < 8; j++) v[j] = *(const f32x4*)(gB + (size_t)(k0 + j) * IN);
#pragma unroll
      for (int i2 = 0; i2 < 4; i2++) {
        bf16x8 o;
#pragma unroll
        for (int j = 0; j < 8; j++) o[j] = (bf16)v[j][i2];
        *(bf16x8*)(Bg + bslot[i2]) = o;
      }
#pragma unroll
      for (int j = 0; j < 8; j++) v[j] = *(const f32x4*)(uB + (size_t)(k0 + j) * IN);
#pragma unroll
      for (int i2 = 0; i2 < 4; i2++) {
        bf16x8 o;
#pragma unroll
        for (int j = 0; j < 8; j++) o[j] = (bf16)v[j][i2];
        *(bf16x8*)(Bu + bslot[i2]) = o;
      }
    }
    __syncthreads();
#pragma unroll
    for (int ks = 0; ks < 2; ks++) {
      int ckf = ks * 4 + (lane >> 4);
      bf16x8 af[4], bgf[4], buf[4];
#pragma unroll
      for (int fm = 0; fm < 4; fm++) {
        int m = wm + fm * 16 + (lane & 15);
        af[fm] = *(const bf16x8*)(As + (m * 8 + (ckf ^ (m & 7))) * 8);
      }
#pragma unroll
      for (int fn = 0; fn < 4; fn++) {
        int n = wn + fn * 16 + (lane & 15);
        int sl = (n * 8 + (ckf ^ (n & 7))) * 8;
        bgf[fn] = *(const bf16x8*)(Bg + sl);
        buf[fn] = *(const bf16x8*)(Bu + sl);
      }
#pragma unroll
      for (int fm = 0; fm < 4; fm++)
#pragma unroll
        for (int fn = 0; fn < 4; fn++) {
          accG[fm][fn] = __builtin_amdgcn_mfma_f32_16x16x32_bf16(af[fm], bgf[fn], accG[fm][fn], 0, 0, 0);
          accU[fm][fn] = __builtin_amdgcn_mfma_f32_16x16x32_bf16(af[fm], buf[fn], accU[fm][fn], 0, 0, 0);
        }
    }
  }
  // epilogue: silu(g)*u*pair_w -> bf16 act
#pragma unroll
  for (int fm = 0; fm < 4; fm++) {
#pragma unroll
    for (int rr = 0; rr < 4; rr++) {
      int m = wm + fm * 16 + ((lane >> 4) << 2) + rr;
      int row = row0 + m;
      if (row < rowend) {
        float pw = perm_w[row];
#pragma unroll
        for (int fn = 0; fn < 4; fn++) {
          int n = nb + wn + fn * 16 + (lane & 15);
          float g = accG[fm][fn][rr], u = accU[fm][fn][rr];
          float sv = g / (1.0f + __expf(-g));
          act[(size_t)row * IN + n] = (bf16)(sv * u * pw);
        }
      }
    }
  }
}

// ---------------- GEMM2: pairout = act @ Dw[e]  (f32 out) ----------------
__launch_bounds__(256, 2)
__global__ void k_gemm2(const bf16* __restrict__ act, const float* __restrict__ dw,
                        const int* __restrict__ tiles, float* __restrict__ pout) {
  int b = blockIdx.x;
  int q = b >> 5, r5 = b & 31;
  int p = q * 8 + (r5 & 7);                 // 0..159
  int slot = (p >> 4) * 4 + (r5 >> 3);
  int e = tiles[slot];
  if (e < 0) return;
  int nt = p & 15;
  int row0 = tiles[MAXMT + slot], rowend = tiles[2 * MAXMT + slot];
  int nb = nt * 128;

  __shared__ bf16 As[128 * 64];
  __shared__ bf16 Bd[128 * 64];

  int tid = threadIdx.x;
  int lane = tid & 63, wave = tid >> 6;
  int wm = (wave >> 1) * 64, wn = (wave & 1) * 64;

  const bf16* aG[4]; bf16* aL[4];
#pragma unroll
  for (int i2 = 0; i2 < 4; i2++) {
    int s = i2 * 256 + tid;
    int r = s >> 3, c = (s & 7) ^ (r & 7);
    int ar = row0 + r; if (ar > NP - 1) ar = NP - 1;
    aG[i2] = act + (size_t)ar * IN + c * 8;
    aL[i2] = As + s * 8;
  }
  int kk = (tid & 7) * 8, nn = (tid >> 3) * 4;
  const float* dB = dw + (size_t)e * IN * HD + (size_t)kk * HD + (nb + nn);
  int bslot[4];
#pragma unroll
  for (int i2 = 0; i2 < 4; i2++) { int n = nn + i2; bslot[i2] = (n * 8 + ((tid & 7) ^ (n & 7))) * 8; }

  f32x4 acc[4][4] = {};

  for (int k0 = 0; k0 < IN; k0 += 64) {
    __syncthreads();
#pragma unroll
    for (int i2 = 0; i2 < 4; i2++) load_lds16(aG[i2] + k0, aL[i2]);
    {
      f32x4 v[8];
#pragma unroll
      for (int j = 0; j < 8; j++) v[j] = *(const f32x4*)(dB + (size_t)(k0 + j) * HD);
#pragma unroll
      for (int i2 = 0; i2 < 4; i2++) {
        bf16x8 o;
#pragma unroll
        for (int j = 0; j < 8; j++) o[j] = (bf16)v[j][i2];
        *(bf16x8*)(Bd + bslot[i2]) = o;
      }
    }
    __syncthreads();
#pragma unroll
    for (int ks = 0; ks < 2; ks++) {
      int ckf = ks * 4 + (lane >> 4);
      bf16x8 af[4], bdf[4];
#pragma unroll
      for (int fm = 0; fm < 4; fm++) {
        int m = wm + fm * 16 + (lane & 15);
        af[fm] = *(const bf16x8*)(As + (m * 8 + (ckf ^ (m & 7))) * 8);
      }
#pragma unroll
      for (int fn = 0; fn < 4; fn++) {
        int n = wn + fn * 16 + (lane & 15);
        bdf[fn] = *(const bf16x8*)(Bd + (n * 8 + (ckf ^ (n & 7))) * 8);
      }
#pragma unroll
      for (int fm = 0; fm < 4; fm++)
#pragma unroll
        for (int fn = 0; fn < 4; fn++)
          acc[fm][fn] = __builtin_amdgcn_mfma_f32_16x16x32_bf16(af[fm], bdf[fn], acc[fm][fn], 0, 0, 0);
    }
  }
#pragma unroll
  for (int fm = 0; fm < 4; fm++) {
#pragma unroll
    for (int rr = 0; rr < 4; rr++) {
      int m = wm + fm * 16 + ((lane >> 4) << 2) + rr;
      int row = row0 + m;
      if (row < rowend) {
#pragma unroll
        for (int fn = 0; fn < 4; fn++) {
          int n = nb + wn + fn * 16 + (lane & 15);
          pout[(size_t)row * HD + n] = acc[fm][fn][rr];
        }
      }
    }
  }
}

// ---------------- combine: out[t] = pout[slot0] + pout[slot1] ----------------
__global__ void k_comb(const float* __restrict__ pout, const int* __restrict__ slot_of,
                       float* __restrict__ out) {
  int i = blockIdx.x * 256 + threadIdx.x;   // covers NT*HD/4
  int t = i >> 9;                            // HD/4 = 512 float4 per row
  int hc = i & 511;
  f32x4 a = ((const f32x4*)(pout + (size_t)slot_of[2 * t] * HD))[hc];
  f32x4 c = ((const f32x4*)(pout + (size_t)slot_of[2 * t + 1] * HD))[hc];
  ((f32x4*)(out + (size_t)t * HD))[hc] = a + c;
}

extern "C" void kernel_launch(void* const* d_in, const int* in_sizes, int n_in,
                              void* d_out, int out_size, void* d_ws, size_t ws_size,
                              hipStream_t stream) {
  const float* hidden  = (const float*)d_in[0];
  const int*   tk_idx  = (const int*)d_in[1];
  const float* tk_w    = (const float*)d_in[2];
  const float* gw      = (const float*)d_in[3];
  const float* uw      = (const float*)d_in[4];
  const float* dw      = (const float*)d_in[5];
  float* out = (float*)d_out;

  char* ws = (char*)d_ws;
  int*   perm_tok = (int*)ws;                               // 16 KB
  float* perm_w   = (float*)(ws + 16384);                   // 16 KB
  int*   slot_of  = (int*)(ws + 32768);                     // 16 KB
  int*   tiles    = (int*)(ws + 49152);                     // ~0.5 KB (reserve 4 KB)
  bf16*  hid_bf   = (bf16*)(ws + 53248);                    // 8 MB
  bf16*  act      = (bf16*)(ws + 53248 + 8388608);          // 11.5 MB
  float* pout     = (float*)(ws + 53248 + 8388608 + 11534336); // 33.5 MB

  k_cvt  <<<4096, 256, 0, stream>>>(hidden, hid_bf);
  k_route<<<1,    256, 0, stream>>>(tk_idx, tk_w, perm_tok, perm_w, slot_of, tiles);
  k_gemm1<<<448,  256, 0, stream>>>(hid_bf, gw, uw, perm_tok, perm_w, tiles, act);
  k_gemm2<<<640,  256, 0, stream>>>(act, dw, tiles, pout);
  k_comb <<<4096, 256, 0, stream>>>(pout, slot_of, out);
}